// Round 1
// baseline (30469.107 us; speedup 1.0000x reference)
//
#include <hip/hip_runtime.h>
#include <hip/hip_cooperative_groups.h>

namespace cg = cooperative_groups;

#define T_STEPS 512
#define BATCH   64
#define DIM     1024
#define HID     1024
#define G4      4096   // 4*HID

// ---------------------------------------------------------------------------
// Kernel A: Xproj[m][n] = dot(inputs[m][:], W_ih[n][:]) + b_ih[n] + b_hh[n]
// M = T*B = 32768, N = 4096, K = 1024. Both operands row-major along K (A·B^T).
// 64x64 tile, 256 threads, 4x4 per thread, kc = 16.
// ---------------------------------------------------------------------------
__global__ __launch_bounds__(256) void xproj_kernel(
    const float* __restrict__ A,    // [M][DIM]
    const float* __restrict__ Wih,  // [G4][DIM]
    const float* __restrict__ b_ih, // [G4]
    const float* __restrict__ b_hh, // [G4]
    float* __restrict__ C)          // [M][G4]
{
    __shared__ float a_s[16][68];   // k-major, padded to 68 (16B-aligned rows, 2-way banks)
    __shared__ float b_s[16][68];

    const int tid = threadIdx.x;
    const int tx  = tid & 15;        // n direction (0..15)
    const int ty  = tid >> 4;        // m direction (0..15)
    const int m0  = blockIdx.y * 64;
    const int n0  = blockIdx.x * 64;

    const int lrow = tid >> 2;       // 0..63
    const int lk4  = (tid & 3) * 4;  // 0,4,8,12

    float acc[4][4] = {};

    for (int k0 = 0; k0 < DIM; k0 += 16) {
        const float4 av = *(const float4*)(A   + (size_t)(m0 + lrow) * DIM + k0 + lk4);
        const float4 bv = *(const float4*)(Wih + (size_t)(n0 + lrow) * DIM + k0 + lk4);
        a_s[lk4 + 0][lrow] = av.x; a_s[lk4 + 1][lrow] = av.y;
        a_s[lk4 + 2][lrow] = av.z; a_s[lk4 + 3][lrow] = av.w;
        b_s[lk4 + 0][lrow] = bv.x; b_s[lk4 + 1][lrow] = bv.y;
        b_s[lk4 + 2][lrow] = bv.z; b_s[lk4 + 3][lrow] = bv.w;
        __syncthreads();
#pragma unroll
        for (int kk = 0; kk < 16; ++kk) {
            const float4 a4 = *(const float4*)&a_s[kk][ty * 4];
            const float4 b4 = *(const float4*)&b_s[kk][tx * 4];
            const float ar[4] = {a4.x, a4.y, a4.z, a4.w};
            const float br[4] = {b4.x, b4.y, b4.z, b4.w};
#pragma unroll
            for (int i = 0; i < 4; ++i)
#pragma unroll
                for (int j = 0; j < 4; ++j)
                    acc[i][j] += ar[i] * br[j];
        }
        __syncthreads();
    }

    const float4 bi = *(const float4*)(b_ih + n0 + tx * 4);
    const float4 bh = *(const float4*)(b_hh + n0 + tx * 4);
    const float bias[4] = {bi.x + bh.x, bi.y + bh.y, bi.z + bh.z, bi.w + bh.w};
#pragma unroll
    for (int i = 0; i < 4; ++i) {
        const int m = m0 + ty * 4 + i;
        float4 v;
        v.x = acc[i][0] + bias[0];
        v.y = acc[i][1] + bias[1];
        v.z = acc[i][2] + bias[2];
        v.w = acc[i][3] + bias[3];
        *(float4*)(C + (size_t)m * G4 + n0 + tx * 4) = v;
    }
}

// ---------------------------------------------------------------------------
// Kernel B: persistent cooperative LSTM recurrence.
// Grid = 256 blocks (1/CU), 256 threads. Block bid owns h-columns
// j0 = bid*4 .. j0+3 and their 4 gate columns each (16 gate cols), all 64 b.
// Per step: gates = Xproj[t] + h·W_hh^T for the 16 cols, then elementwise
// update; c state lives in LDS for the whole kernel.
// K split 4-way across the 4 waves (ks), each wave stages its own k-chunk.
// LDS layouts are transposed (k-major) and padded so all compute reads are
// conflict-free (<=2-way).
// ---------------------------------------------------------------------------
__global__ __launch_bounds__(256) void lstm_recurrent(
    const float* __restrict__ Xproj,  // [T][B][G4]
    const float* __restrict__ h0,     // [B][HID]
    const float* __restrict__ c0,     // [B][HID]
    const float* __restrict__ Whh,    // [G4][HID]
    float* __restrict__ hbuf0,        // [B][HID]
    float* __restrict__ hbuf1,        // [B][HID]
    float* __restrict__ out)          // [T][B][HID] ++ hT [B][HID] ++ cT [B][HID]
{
    cg::grid_group grid = cg::this_grid();

    // 4 ksplit groups x 32 k-slots x 64 b (stride 65): 33280 B
    __shared__ float h_s[4][32][65];
    // 4 ksplit groups x 32 k-slots x 16 c (stride 17): 8704 B
    __shared__ float w_s[4][32][17];
    __shared__ float gates_s[64][17];  // [b][g*4+jj], 4352 B
    __shared__ float c_s[64][4];       // persistent cell state, 1024 B
    // partials alias h_s (used only after the last chunk's compute, before
    // the next step's staging — separated by barriers/grid.sync)
    float* part_s = &h_s[0][0][0];     // [256][17] floats = 17408 B <= 33280 B

    const int bid = blockIdx.x;        // 0..255
    const int tid = threadIdx.x;       // 0..255
    const int j0  = bid * 4;
    const int ks  = tid >> 6;          // wave id = ksplit group, k in [ks*256, ks*256+256)
    const int gl  = tid & 63;          // lane within wave
    const int bg  = gl >> 2;  const int b0  = bg * 4;   // batch quad
    const int cgi = gl & 3;   const int c0_ = cgi * 4;  // col quad (cgi == gate id)

    // init persistent c state and h double-buffer slice
    {
        const int b = tid >> 2, jj = tid & 3;
        c_s[b][jj] = c0[b * HID + j0 + jj];
        hbuf0[b * HID + j0 + jj] = h0[b * HID + j0 + jj];
    }
    grid.sync();

    for (int t = 0; t < T_STEPS; ++t) {
        const float* __restrict__ hread  = (t & 1) ? hbuf1 : hbuf0;
        float* __restrict__       hwrite = (t & 1) ? hbuf0 : hbuf1;

        float acc[4][4] = {};

        const int kbase0 = ks * 256;
        for (int ci = 0; ci < 8; ++ci) {
            const int kb = kbase0 + ci * 32;
            // --- stage h chunk: 64 b x 32 k -> h_s[ks][k][b] (transposed) ---
#pragma unroll
            for (int r = 0; r < 8; ++r) {
                const int fidx = r * 64 + gl;      // 0..511 float4s
                const int b    = fidx >> 3;        // 0..63
                const int k4   = (fidx & 7) * 4;   // 0..28
                const float4 v = *(const float4*)(hread + b * HID + kb + k4);
                h_s[ks][k4 + 0][b] = v.x;
                h_s[ks][k4 + 1][b] = v.y;
                h_s[ks][k4 + 2][b] = v.z;
                h_s[ks][k4 + 3][b] = v.w;
            }
            // --- stage w chunk: 16 c x 32 k -> w_s[ks][k][c] (transposed) ---
#pragma unroll
            for (int r = 0; r < 2; ++r) {
                const int fidx = r * 64 + gl;      // 0..127 float4s
                const int c    = fidx >> 3;        // 0..15
                const int k4   = (fidx & 7) * 4;
                const int n    = (c >> 2) * HID + j0 + (c & 3);
                const float4 v = *(const float4*)(Whh + (size_t)n * HID + kb + k4);
                w_s[ks][k4 + 0][c] = v.x;
                w_s[ks][k4 + 1][c] = v.y;
                w_s[ks][k4 + 2][c] = v.z;
                w_s[ks][k4 + 3][c] = v.w;
            }
            __syncthreads();
            // --- compute: 4b x 4c per thread over 32 k ---
#pragma unroll 16
            for (int kk = 0; kk < 32; ++kk) {
                float hv[4], wv[4];
#pragma unroll
                for (int i = 0; i < 4; ++i) hv[i] = h_s[ks][kk][b0 + i];
#pragma unroll
                for (int j = 0; j < 4; ++j) wv[j] = w_s[ks][kk][c0_ + j];
#pragma unroll
                for (int i = 0; i < 4; ++i)
#pragma unroll
                    for (int j = 0; j < 4; ++j)
                        acc[i][j] += hv[i] * wv[j];
            }
            __syncthreads();
        }

        // --- reduce the 4 ksplit partials ---
#pragma unroll
        for (int i = 0; i < 4; ++i)
#pragma unroll
            for (int j = 0; j < 4; ++j)
                part_s[tid * 17 + i * 4 + j] = acc[i][j];
        __syncthreads();
        if (ks == 0) {
#pragma unroll
            for (int i = 0; i < 4; ++i)
#pragma unroll
                for (int j = 0; j < 4; ++j) {
                    const int idx = i * 4 + j;
                    const float s = part_s[gl * 17 + idx] +
                                    part_s[(gl + 64) * 17 + idx] +
                                    part_s[(gl + 128) * 17 + idx] +
                                    part_s[(gl + 192) * 17 + idx];
                    gates_s[b0 + i][c0_ + j] = s;
                }
        }
        __syncthreads();

        // --- elementwise LSTM cell update: thread -> (b, jj) ---
        {
            const int b  = tid >> 2;
            const int jj = tid & 3;
            const int j  = j0 + jj;
            const float* xp = Xproj + ((size_t)t * BATCH + b) * G4;
            const float pre_i = gates_s[b][0 * 4 + jj] + xp[0 * HID + j];
            const float pre_f = gates_s[b][1 * 4 + jj] + xp[1 * HID + j];
            const float pre_g = gates_s[b][2 * 4 + jj] + xp[2 * HID + j];
            const float pre_o = gates_s[b][3 * 4 + jj] + xp[3 * HID + j];
            const float ig = 1.0f / (1.0f + __expf(-pre_i));
            const float fg = 1.0f / (1.0f + __expf(-pre_f));
            const float gg = tanhf(pre_g);
            const float og = 1.0f / (1.0f + __expf(-pre_o));
            const float cn = fg * c_s[b][jj] + ig * gg;
            const float hn = og * tanhf(cn);
            c_s[b][jj] = cn;
            hwrite[b * HID + j] = hn;
            out[((size_t)t * BATCH + b) * HID + j] = hn;
            if (t == T_STEPS - 1) {
                out[(size_t)T_STEPS * BATCH * HID + (size_t)b * HID + j] = hn;
                out[(size_t)T_STEPS * BATCH * HID + (size_t)BATCH * HID + (size_t)b * HID + j] = cn;
            }
        }
        __syncthreads();   // protect gates_s/c_s before next step reuses LDS
        grid.sync();       // h double-buffer handoff (release/acquire device scope)
    }
}

// ---------------------------------------------------------------------------
extern "C" void kernel_launch(void* const* d_in, const int* in_sizes, int n_in,
                              void* d_out, int out_size, void* d_ws, size_t ws_size,
                              hipStream_t stream) {
    const float* inputs = (const float*)d_in[0];  // [T][B][DIM]
    const float* h0     = (const float*)d_in[1];  // [B][HID]
    const float* c0     = (const float*)d_in[2];  // [B][HID]
    const float* W_ih   = (const float*)d_in[3];  // [G4][DIM]
    const float* W_hh   = (const float*)d_in[4];  // [G4][HID]
    const float* b_ih   = (const float*)d_in[5];  // [G4]
    const float* b_hh   = (const float*)d_in[6];  // [G4]
    float* out = (float*)d_out;

    float* Xproj = (float*)d_ws;                                   // T*B*G4 floats = 512 MB
    float* hbuf0 = Xproj + (size_t)T_STEPS * BATCH * G4;           // B*HID
    float* hbuf1 = hbuf0 + (size_t)BATCH * HID;                    // B*HID

    // Kernel A: input projection GEMM
    dim3 gridA(G4 / 64, (T_STEPS * BATCH) / 64);
    xproj_kernel<<<gridA, dim3(256), 0, stream>>>(inputs, W_ih, b_ih, b_hh, Xproj);

    // Kernel B: persistent cooperative recurrence
    void* args[] = {(void*)&Xproj, (void*)&h0, (void*)&c0, (void*)&W_hh,
                    (void*)&hbuf0, (void*)&hbuf1, (void*)&out};
    hipLaunchCooperativeKernel((void*)lstm_recurrent, dim3(256), dim3(256),
                               args, 0, stream);
}